// Round 19
// baseline (143.472 us; speedup 1.0000x reference)
//
#include <hip/hip_runtime.h>
#include <math.h>

#define DD 2048
#define EE 64
#define KQ 32
#define TOKTILE 128

// ---------------- K1a: gate GEMM, ksplit=8, 4x8 tile (R13 verbatim, 79us) ----
__global__ __launch_bounds__(256, 4) void sr_gemm8(
    const float* __restrict__ x, const float* __restrict__ wg,
    float* __restrict__ partial, int N)
{
  __shared__ float xs[KQ][TOKTILE];
  __shared__ float wsh[KQ][EE];
  const int ntiles = N / TOKTILE;
  const int tt = blockIdx.x % ntiles;
  const int kc = blockIdx.x / ntiles;
  const int kblk = DD / 8;
  const int nchunk = kblk / KQ;
  const int k0 = kc * kblk;
  const int t0 = tt * TOKTILE;
  const int tid = threadIdx.x;
  const int ti = tid & 31;
  const int tj = tid >> 5;

  float acc[4][8];
#pragma unroll
  for (int r = 0; r < 4; ++r)
#pragma unroll
    for (int c = 0; c < 8; ++c) acc[r][c] = 0.f;

  const int srowbase = tid >> 3;
  const int c4 = (tid & 7) * 4;
  const int swz = 8 * (tid & 3);

  for (int ch = 0; ch < nchunk; ++ch) {
    const int kb = k0 + ch * KQ;
#pragma unroll
    for (int p = 0; p < 4; ++p) {
      const int row = p * 32 + srowbase;
      const float4 v = *reinterpret_cast<const float4*>(
          &x[(size_t)(t0 + row) * DD + kb + c4]);
      const int srow = row ^ swz;
      xs[c4 + 0][srow] = v.x;
      xs[c4 + 1][srow] = v.y;
      xs[c4 + 2][srow] = v.z;
      xs[c4 + 3][srow] = v.w;
    }
    {
      const int e = tid >> 2;
      const int kq = (tid & 3) * 8;
      const float4 a = *reinterpret_cast<const float4*>(&wg[(size_t)e * DD + kb + kq]);
      const float4 b = *reinterpret_cast<const float4*>(&wg[(size_t)e * DD + kb + kq + 4]);
      wsh[kq + 0][e] = a.x; wsh[kq + 1][e] = a.y; wsh[kq + 2][e] = a.z; wsh[kq + 3][e] = a.w;
      wsh[kq + 4][e] = b.x; wsh[kq + 5][e] = b.y; wsh[kq + 6][e] = b.z; wsh[kq + 7][e] = b.w;
    }
    __syncthreads();
#pragma unroll 8
    for (int k = 0; k < KQ; ++k) {
      const int sk = 8 * ((k >> 2) & 3);
      float xv[4], wv[8];
      *reinterpret_cast<float4*>(&xv[0]) =
          *reinterpret_cast<const float4*>(&xs[k][(4 * ti) ^ sk]);
      *reinterpret_cast<float4*>(&wv[0]) = *reinterpret_cast<const float4*>(&wsh[k][8 * tj]);
      *reinterpret_cast<float4*>(&wv[4]) = *reinterpret_cast<const float4*>(&wsh[k][8 * tj + 4]);
#pragma unroll
      for (int r = 0; r < 4; ++r)
#pragma unroll
        for (int c = 0; c < 8; ++c) acc[r][c] = fmaf(xv[r], wv[c], acc[r][c]);
    }
    __syncthreads();
  }
#pragma unroll
  for (int c = 0; c < 8; ++c) {
    const int e = 8 * tj + c;
    const float4 v = make_float4(acc[0][c], acc[1][c], acc[2][c], acc[3][c]);
    *reinterpret_cast<float4*>(&partial[((size_t)kc * EE + e) * N + t0 + 4 * ti]) = v;
  }
}

// ---------------- K1b: gate GEMM, ksplit=16, 8x8 tile ----------------
// Same two-barrier structure and wave geometry as the proven 79us kernel
// (4 blocks/CU x 4 waves = 4 waves/SIMD) but 64 outputs/thread: DS drops to
// 4 b128 per 64 FMA-instr -> VALU ceiling 512/768 = 67% (was 44%).
// KQ=16 keeps LDS at 20KB/block. kblk=128 -> fp32 fmaf chain is 128-long
// (numerics shift ~1ulp vs 256-long; f64 c-order combine unchanged).
#define TOK16 256
#define KQ2 16
__global__ __launch_bounds__(256, 4) void sr_gemm16(
    const float* __restrict__ x, const float* __restrict__ wg,
    float* __restrict__ partial, int N)
{
  __shared__ float xs[KQ2][TOK16];  // 16 KB, swizzled (t ^ 8*((k>>2)&3))
  __shared__ float wsh[KQ2][EE];    // 4 KB
  const int ntiles = N / TOK16;     // 64
  const int tt = blockIdx.x % ntiles;
  const int kc = blockIdx.x / ntiles;  // 0..15
  const int kblk = DD / 16;         // 128
  const int nchunk = kblk / KQ2;    // 8
  const int k0 = kc * kblk;
  const int t0 = tt * TOK16;
  const int tid = threadIdx.x;
  const int ti = tid & 31;   // token octet: tokens 8*ti .. 8*ti+7
  const int tj = tid >> 5;   // expert octet: experts 8*tj .. 8*tj+7

  float acc[8][8];
#pragma unroll
  for (int r = 0; r < 8; ++r)
#pragma unroll
    for (int c = 0; c < 8; ++c) acc[r][c] = 0.f;

  // x staging: 4 passes x 64 rows; 4 thr/row (64B contiguous per row-chunk)
  const int srowb = tid >> 2;           // 0..63
  const int c4s = (tid & 3) * 4;        // k quad base (0..12)
  const int swz = 8 * (tid & 3);        // == 8*(((c4s+j)>>2)&3)
  // w staging: 4 thr/expert row, 4 k each
  const int we = tid >> 2;              // 0..63
  const int wk4 = (tid & 3) * 4;

  for (int ch = 0; ch < nchunk; ++ch) {
    const int kb = k0 + ch * KQ2;
#pragma unroll
    for (int p = 0; p < 4; ++p) {
      const int row = p * 64 + srowb;
      const float4 v = *reinterpret_cast<const float4*>(
          &x[(size_t)(t0 + row) * DD + kb + c4s]);
      const int srow = row ^ swz;       // 2-way bank spread on writes
      xs[c4s + 0][srow] = v.x;
      xs[c4s + 1][srow] = v.y;
      xs[c4s + 2][srow] = v.z;
      xs[c4s + 3][srow] = v.w;
    }
    {
      const float4 a = *reinterpret_cast<const float4*>(
          &wg[(size_t)we * DD + kb + wk4]);
      wsh[wk4 + 0][we] = a.x;
      wsh[wk4 + 1][we] = a.y;
      wsh[wk4 + 2][we] = a.z;
      wsh[wk4 + 3][we] = a.w;
    }
    __syncthreads();
#pragma unroll
    for (int k = 0; k < KQ2; ++k) {
      const int sk = 8 * ((k >> 2) & 3);
      const int xb = (8 * ti) ^ sk;  // +m stays in-range: sk has no bits 0-2
      float xv[8], wv[8];
      *reinterpret_cast<float4*>(&xv[0]) =
          *reinterpret_cast<const float4*>(&xs[k][xb]);
      *reinterpret_cast<float4*>(&xv[4]) =
          *reinterpret_cast<const float4*>(&xs[k][xb + 4]);
      *reinterpret_cast<float4*>(&wv[0]) =
          *reinterpret_cast<const float4*>(&wsh[k][8 * tj]);
      *reinterpret_cast<float4*>(&wv[4]) =
          *reinterpret_cast<const float4*>(&wsh[k][8 * tj + 4]);
#pragma unroll
      for (int r = 0; r < 8; ++r)
#pragma unroll
        for (int c = 0; c < 8; ++c) acc[r][c] = fmaf(xv[r], wv[c], acc[r][c]);
    }
    __syncthreads();
  }
#pragma unroll
  for (int c = 0; c < 8; ++c) {
    const int e = 8 * tj + c;
    const size_t base = ((size_t)kc * EE + e) * N + t0 + 8 * ti;
    *reinterpret_cast<float4*>(&partial[base]) =
        make_float4(acc[0][c], acc[1][c], acc[2][c], acc[3][c]);
    *reinterpret_cast<float4*>(&partial[base + 4]) =
        make_float4(acc[4][c], acc[5][c], acc[6][c], acc[7][c]);
  }
}

// ---------------- K2: cross-ksplit reduction (templated, unrolled) ----------
template <int KS>
__global__ __launch_bounds__(256) void sr_reduceT(
    const float* __restrict__ partial, float* __restrict__ logits,
    int* __restrict__ counts, int N)
{
  if (blockIdx.x == 0 && threadIdx.x < EE) counts[threadIdx.x] = 0;
  const int i4 = blockIdx.x * 256 + threadIdx.x;
  const size_t base = (size_t)i4 * 4;
  if (base >= (size_t)EE * N) return;
  const size_t cs = (size_t)EE * N;
  double s0 = 0.0, s1 = 0.0, s2 = 0.0, s3 = 0.0;
#pragma unroll
  for (int c = 0; c < KS; ++c) {
    const float4 v = *reinterpret_cast<const float4*>(&partial[c * cs + base]);
    s0 += (double)v.x; s1 += (double)v.y; s2 += (double)v.z; s3 += (double)v.w;
  }
  *reinterpret_cast<float4*>(&logits[base]) =
      make_float4((float)s0, (float)s1, (float)s2, (float)s3);
}

// ---------------- K3: per-token softmax/argmax (128 tok / 256 thr blocks) ----
__global__ __launch_bounds__(256) void sr_softmax(
    const float* __restrict__ logits, float* __restrict__ dout,
    float* __restrict__ ws_w, int* __restrict__ ws_idx,
    int* __restrict__ counts, float* __restrict__ probsum, int N)
{
  __shared__ float lp[128][EE + 1];
  __shared__ float psq[4][EE];
  const int tid = threadIdx.x;
  const int t0 = blockIdx.x * 128;
  if (tid < 128) {
    const int t = t0 + tid;
    float l[EE];
    float maxv = -3.0e38f;
    int arg = 0;
#pragma unroll
    for (int e = 0; e < EE; ++e) {
      l[e] = logits[(size_t)e * N + t];
      if (l[e] > maxv) { maxv = l[e]; arg = e; }  // strict > : first max wins
    }
    float s = 0.f;
#pragma unroll
    for (int e = 0; e < EE; ++e) {
      const float ex = __expf(l[e] - maxv);
      lp[tid][e] = ex;
      s += ex;
    }
    const float inv = 1.0f / s;
    const float w = inv;  // exp(0)/sum
#pragma unroll
    for (int e = 0; e < EE; ++e) lp[tid][e] *= inv;
    dout[t] = w;
    dout[N + t] = (float)arg;
    ws_w[t] = w;
    ws_idx[t] = arg;
    atomicAdd(&counts[arg], 1);
  }
  __syncthreads();
  const int e = tid & 63, q = tid >> 6;
  float ps = 0.f;
  for (int r = 0; r < 32; ++r) ps += lp[q * 32 + r][e];
  psq[q][e] = ps;
  __syncthreads();
  if (tid < 64) {
    const float tot = ((psq[0][tid] + psq[1][tid]) + psq[2][tid]) + psq[3][tid];
    probsum[(size_t)blockIdx.x * EE + tid] = tot;
  }
}

// ---------------- K4: fused stats + select + apply (one 1024-thr block) ----
__device__ __forceinline__ int sr_bsum(int c, int red[][16], int pc, int tid) {
#pragma unroll
  for (int off = 32; off > 0; off >>= 1) c += __shfl_down(c, off, 64);
  if ((tid & 63) == 0) red[pc & 1][tid >> 6] = c;
  __syncthreads();
  int s = 0;
#pragma unroll
  for (int i = 0; i < 16; ++i) s += red[pc & 1][i];
  return s;
}

__global__ __launch_bounds__(1024) void sr_finish(
    const float* __restrict__ probsum, const int* __restrict__ counts,
    const float* __restrict__ ws_w, const int* __restrict__ ws_idx,
    float* __restrict__ dout, int N, int nblocks, int cap)
{
  __shared__ double dseg[16][EE];
  __shared__ double mean_s[EE];
  __shared__ int cnt_s[EE];
  __shared__ int hdr[2];
  __shared__ int red[2][16];
  const int tid = threadIdx.x;
  const int PER = N / 1024;  // 16

  float wv[16];
  int iv[16];
#pragma unroll
  for (int r = 0; r < 16; ++r) {
    float w = 0.f; int ix = -1;
    if (r < PER) {
      const int i = tid + r * 1024;
      w = ws_w[i];
      ix = ws_idx[i];
    }
    wv[r] = w; iv[r] = ix;
  }

  {
    const int e = tid & 63, seg = tid >> 6;
    const int per = nblocks / 16;
    double ps = 0.0;
    for (int b = seg * per; b < (seg + 1) * per; ++b)
      ps += (double)probsum[(size_t)b * EE + e];
    dseg[seg][e] = ps;
  }
  __syncthreads();
  if (tid < 64) {
    double tot = 0.0;
#pragma unroll
    for (int s2 = 0; s2 < 16; ++s2) tot += dseg[s2][tid];
    const int cnt = counts[tid];
    dout[2 * N + tid] = (float)cnt;
    mean_s[tid] = tot / (double)N;
    cnt_s[tid] = cnt;
  }
  __syncthreads();
  if (tid == 0) {
    double aux = 0.0;
    int nover = 0, e1 = -1;
    for (int i = 0; i < EE; ++i) {
      aux += ((double)cnt_s[i] / (double)N) * mean_s[i];
      if (cnt_s[i] > cap) { if (nover == 0) e1 = i; ++nover; }
    }
    dout[2 * N + EE] = (float)(aux * (double)EE);
    hdr[0] = (nover >= 2) ? 2 : nover;
    hdr[1] = e1;
  }
  __syncthreads();
  const int mode = hdr[0];

  if (mode == 0) return;
  if (mode == 2) {
#pragma unroll
    for (int r = 0; r < 16; ++r)
      if (r < PER) dout[tid + r * 1024] = 0.f;
    return;
  }

  const int e1 = hdr[1];
  unsigned mb[16];
#pragma unroll
  for (int r = 0; r < 16; ++r)
    mb[r] = (iv[r] == e1) ? __float_as_uint(wv[r]) : 0u;

  int pc = 0;
  unsigned lo = 0x3C000000u, hi = 0x3F800000u;
  while (hi - lo > 1u) {
    const unsigned mid = lo + ((hi - lo) >> 1);
    int c = 0;
#pragma unroll
    for (int r = 0; r < 16; ++r) c += (mb[r] >= mid);
    const int tot = sr_bsum(c, red, pc++, tid);
    if (tot >= cap) lo = mid; else hi = mid;
  }
  int cge = 0, cgt = 0;
#pragma unroll
  for (int r = 0; r < 16; ++r) {
    cge += (mb[r] >= lo);
    cgt += (mb[r] > lo);
  }
  const int tot_ge = sr_bsum(cge, red, pc++, tid);
  const int tot_gt = sr_bsum(cgt, red, pc++, tid);
  const int quota = cap - tot_gt;
  int idx_thr = N - 1;
  if (tot_ge - tot_gt > quota) {
    int l2 = -1, h2 = N - 1;
    while (h2 - l2 > 1) {
      const int mid = (l2 + h2) >> 1;
      int c = 0;
#pragma unroll
      for (int r = 0; r < 16; ++r) {
        const int i = tid + r * 1024;
        c += (mb[r] == lo && i <= mid) ? 1 : 0;
      }
      const int tot = sr_bsum(c, red, pc++, tid);
      if (tot >= quota) h2 = mid; else l2 = mid;
    }
    idx_thr = h2;
  }

#pragma unroll
  for (int r = 0; r < 16; ++r) {
    if (r < PER) {
      const int i = tid + r * 1024;
      const bool keep = (mb[r] > lo) || (mb[r] == lo && i <= idx_thr);
      dout[i] = keep ? wv[r] : 0.f;
    }
  }
}

// ---------------- launch ----------------
extern "C" void kernel_launch(void* const* d_in, const int* in_sizes, int n_in,
                              void* d_out, int out_size, void* d_ws, size_t ws_size,
                              hipStream_t stream)
{
  const float* x = (const float*)d_in[0];
  const float* wg = (const float*)d_in[1];
  const int N = in_sizes[0] / DD;  // 16384
  float* dout = (float*)d_out;
  float* wsf = (float*)d_ws;

  float* ws_w = wsf;
  int* ws_idx = (int*)(wsf + N);
  int* counts = (int*)(wsf + 2 * (size_t)N);
  float* probsum = wsf + 2 * (size_t)N + EE;
  const int nblocks_sm = N / 128;
  float* logits = wsf + 2 * (size_t)N + EE + (size_t)nblocks_sm * EE;
  float* partial = logits + (size_t)EE * N;
  const size_t base_floats = 2 * (size_t)N + EE + (size_t)nblocks_sm * EE + (size_t)EE * N;
  const int cap = (int)((double)N * 1.25 / (double)EE);  // 320

  const bool use16 =
      (base_floats + (size_t)16 * EE * (size_t)N) * sizeof(float) <= ws_size;

  if (use16) {
    sr_gemm16<<<(N / TOK16) * 16, 256, 0, stream>>>(x, wg, partial, N);
    sr_reduceT<16><<<(EE * N / 4 + 255) / 256, 256, 0, stream>>>(partial, logits, counts, N);
  } else {
    sr_gemm8<<<(N / TOKTILE) * 8, 256, 0, stream>>>(x, wg, partial, N);
    sr_reduceT<8><<<(EE * N / 4 + 255) / 256, 256, 0, stream>>>(partial, logits, counts, N);
  }
  sr_softmax<<<N / 128, 256, 0, stream>>>(logits, dout, ws_w, ws_idx, counts, probsum, N);
  sr_finish<<<1, 1024, 0, stream>>>(probsum, counts, ws_w, ws_idx, dout, N, nblocks_sm, cap);
}

// Round 20
// 142.960 us; speedup vs baseline: 1.0036x; 1.0036x over previous
//
#include <hip/hip_runtime.h>
#include <math.h>

#define DD 2048
#define EE 64
#define KQ 32
#define TOKTILE 128

// ---------------- K1a: gate GEMM, ksplit=8, 4x8 tile (R13 verbatim, 79us) ----
__global__ __launch_bounds__(256, 4) void sr_gemm8(
    const float* __restrict__ x, const float* __restrict__ wg,
    float* __restrict__ partial, int N)
{
  __shared__ float xs[KQ][TOKTILE];
  __shared__ float wsh[KQ][EE];
  const int ntiles = N / TOKTILE;
  const int tt = blockIdx.x % ntiles;
  const int kc = blockIdx.x / ntiles;
  const int kblk = DD / 8;
  const int nchunk = kblk / KQ;
  const int k0 = kc * kblk;
  const int t0 = tt * TOKTILE;
  const int tid = threadIdx.x;
  const int ti = tid & 31;
  const int tj = tid >> 5;

  float acc[4][8];
#pragma unroll
  for (int r = 0; r < 4; ++r)
#pragma unroll
    for (int c = 0; c < 8; ++c) acc[r][c] = 0.f;

  const int srowbase = tid >> 3;
  const int c4 = (tid & 7) * 4;
  const int swz = 8 * (tid & 3);

  for (int ch = 0; ch < nchunk; ++ch) {
    const int kb = k0 + ch * KQ;
#pragma unroll
    for (int p = 0; p < 4; ++p) {
      const int row = p * 32 + srowbase;
      const float4 v = *reinterpret_cast<const float4*>(
          &x[(size_t)(t0 + row) * DD + kb + c4]);
      const int srow = row ^ swz;
      xs[c4 + 0][srow] = v.x;
      xs[c4 + 1][srow] = v.y;
      xs[c4 + 2][srow] = v.z;
      xs[c4 + 3][srow] = v.w;
    }
    {
      const int e = tid >> 2;
      const int kq = (tid & 3) * 8;
      const float4 a = *reinterpret_cast<const float4*>(&wg[(size_t)e * DD + kb + kq]);
      const float4 b = *reinterpret_cast<const float4*>(&wg[(size_t)e * DD + kb + kq + 4]);
      wsh[kq + 0][e] = a.x; wsh[kq + 1][e] = a.y; wsh[kq + 2][e] = a.z; wsh[kq + 3][e] = a.w;
      wsh[kq + 4][e] = b.x; wsh[kq + 5][e] = b.y; wsh[kq + 6][e] = b.z; wsh[kq + 7][e] = b.w;
    }
    __syncthreads();
#pragma unroll 8
    for (int k = 0; k < KQ; ++k) {
      const int sk = 8 * ((k >> 2) & 3);
      float xv[4], wv[8];
      *reinterpret_cast<float4*>(&xv[0]) =
          *reinterpret_cast<const float4*>(&xs[k][(4 * ti) ^ sk]);
      *reinterpret_cast<float4*>(&wv[0]) = *reinterpret_cast<const float4*>(&wsh[k][8 * tj]);
      *reinterpret_cast<float4*>(&wv[4]) = *reinterpret_cast<const float4*>(&wsh[k][8 * tj + 4]);
#pragma unroll
      for (int r = 0; r < 4; ++r)
#pragma unroll
        for (int c = 0; c < 8; ++c) acc[r][c] = fmaf(xv[r], wv[c], acc[r][c]);
    }
    __syncthreads();
  }
#pragma unroll
  for (int c = 0; c < 8; ++c) {
    const int e = 8 * tj + c;
    const float4 v = make_float4(acc[0][c], acc[1][c], acc[2][c], acc[3][c]);
    *reinterpret_cast<float4*>(&partial[((size_t)kc * EE + e) * N + t0 + 4 * ti]) = v;
  }
}

// ---------------- K1b: gate GEMM, ksplit=16, 8x8 tile ----------------
// R19 geometry, with the regalloc pinned: amdgpu_waves_per_eu(4,4) forces
// VGPR budget 512/4=128 so the 64-acc thread state FITS (R19: compiler chose
// 64 VGPR for 8 waves/SIMD and spilled acc to scratch -> VALU 25%).
// DS ratio: 4 b128 per 64 FMA-instr -> VALU ceiling 512/768 = 67%.
#define TOK16 256
#define KQ2 16
__global__ __launch_bounds__(256)
__attribute__((amdgpu_waves_per_eu(4, 4)))
void sr_gemm16(
    const float* __restrict__ x, const float* __restrict__ wg,
    float* __restrict__ partial, int N)
{
  __shared__ float xs[KQ2][TOK16];  // 16 KB, swizzled (t ^ 8*((k>>2)&3))
  __shared__ float wsh[KQ2][EE];    // 4 KB
  const int ntiles = N / TOK16;     // 64
  const int tt = blockIdx.x % ntiles;
  const int kc = blockIdx.x / ntiles;  // 0..15
  const int kblk = DD / 16;         // 128
  const int nchunk = kblk / KQ2;    // 8
  const int k0 = kc * kblk;
  const int t0 = tt * TOK16;
  const int tid = threadIdx.x;
  const int ti = tid & 31;   // token octet: tokens 8*ti .. 8*ti+7
  const int tj = tid >> 5;   // expert octet: experts 8*tj .. 8*tj+7

  float acc[8][8];
#pragma unroll
  for (int r = 0; r < 8; ++r)
#pragma unroll
    for (int c = 0; c < 8; ++c) acc[r][c] = 0.f;

  // x staging: 4 passes x 64 rows; 4 thr/row (64B contiguous per row-chunk)
  const int srowb = tid >> 2;           // 0..63
  const int c4s = (tid & 3) * 4;        // k quad base (0..12)
  const int swz = 8 * (tid & 3);        // == 8*(((c4s+j)>>2)&3)
  // w staging: 4 thr/expert row, 4 k each
  const int we = tid >> 2;              // 0..63
  const int wk4 = (tid & 3) * 4;

  for (int ch = 0; ch < nchunk; ++ch) {
    const int kb = k0 + ch * KQ2;
#pragma unroll
    for (int p = 0; p < 4; ++p) {
      const int row = p * 64 + srowb;
      const float4 v = *reinterpret_cast<const float4*>(
          &x[(size_t)(t0 + row) * DD + kb + c4s]);
      const int srow = row ^ swz;       // 2-way bank spread on writes
      xs[c4s + 0][srow] = v.x;
      xs[c4s + 1][srow] = v.y;
      xs[c4s + 2][srow] = v.z;
      xs[c4s + 3][srow] = v.w;
    }
    {
      const float4 a = *reinterpret_cast<const float4*>(
          &wg[(size_t)we * DD + kb + wk4]);
      wsh[wk4 + 0][we] = a.x;
      wsh[wk4 + 1][we] = a.y;
      wsh[wk4 + 2][we] = a.z;
      wsh[wk4 + 3][we] = a.w;
    }
    __syncthreads();
#pragma unroll
    for (int k = 0; k < KQ2; ++k) {
      const int sk = 8 * ((k >> 2) & 3);
      const int xb = (8 * ti) ^ sk;  // +m stays in-range: sk has no bits 0-2
      float xv[8], wv[8];
      *reinterpret_cast<float4*>(&xv[0]) =
          *reinterpret_cast<const float4*>(&xs[k][xb]);
      *reinterpret_cast<float4*>(&xv[4]) =
          *reinterpret_cast<const float4*>(&xs[k][xb + 4]);
      *reinterpret_cast<float4*>(&wv[0]) =
          *reinterpret_cast<const float4*>(&wsh[k][8 * tj]);
      *reinterpret_cast<float4*>(&wv[4]) =
          *reinterpret_cast<const float4*>(&wsh[k][8 * tj + 4]);
#pragma unroll
      for (int r = 0; r < 8; ++r)
#pragma unroll
        for (int c = 0; c < 8; ++c) acc[r][c] = fmaf(xv[r], wv[c], acc[r][c]);
    }
    __syncthreads();
  }
#pragma unroll
  for (int c = 0; c < 8; ++c) {
    const int e = 8 * tj + c;
    const size_t base = ((size_t)kc * EE + e) * N + t0 + 8 * ti;
    *reinterpret_cast<float4*>(&partial[base]) =
        make_float4(acc[0][c], acc[1][c], acc[2][c], acc[3][c]);
    *reinterpret_cast<float4*>(&partial[base + 4]) =
        make_float4(acc[4][c], acc[5][c], acc[6][c], acc[7][c]);
  }
}

// ---------------- K2: cross-ksplit reduction (templated, unrolled) ----------
template <int KS>
__global__ __launch_bounds__(256) void sr_reduceT(
    const float* __restrict__ partial, float* __restrict__ logits,
    int* __restrict__ counts, int N)
{
  if (blockIdx.x == 0 && threadIdx.x < EE) counts[threadIdx.x] = 0;
  const int i4 = blockIdx.x * 256 + threadIdx.x;
  const size_t base = (size_t)i4 * 4;
  if (base >= (size_t)EE * N) return;
  const size_t cs = (size_t)EE * N;
  double s0 = 0.0, s1 = 0.0, s2 = 0.0, s3 = 0.0;
#pragma unroll
  for (int c = 0; c < KS; ++c) {
    const float4 v = *reinterpret_cast<const float4*>(&partial[c * cs + base]);
    s0 += (double)v.x; s1 += (double)v.y; s2 += (double)v.z; s3 += (double)v.w;
  }
  *reinterpret_cast<float4*>(&logits[base]) =
      make_float4((float)s0, (float)s1, (float)s2, (float)s3);
}

// ---------------- K3: per-token softmax/argmax (128 tok / 256 thr blocks) ----
__global__ __launch_bounds__(256) void sr_softmax(
    const float* __restrict__ logits, float* __restrict__ dout,
    float* __restrict__ ws_w, int* __restrict__ ws_idx,
    int* __restrict__ counts, float* __restrict__ probsum, int N)
{
  __shared__ float lp[128][EE + 1];
  __shared__ float psq[4][EE];
  const int tid = threadIdx.x;
  const int t0 = blockIdx.x * 128;
  if (tid < 128) {
    const int t = t0 + tid;
    float l[EE];
    float maxv = -3.0e38f;
    int arg = 0;
#pragma unroll
    for (int e = 0; e < EE; ++e) {
      l[e] = logits[(size_t)e * N + t];
      if (l[e] > maxv) { maxv = l[e]; arg = e; }  // strict > : first max wins
    }
    float s = 0.f;
#pragma unroll
    for (int e = 0; e < EE; ++e) {
      const float ex = __expf(l[e] - maxv);
      lp[tid][e] = ex;
      s += ex;
    }
    const float inv = 1.0f / s;
    const float w = inv;  // exp(0)/sum
#pragma unroll
    for (int e = 0; e < EE; ++e) lp[tid][e] *= inv;
    dout[t] = w;
    dout[N + t] = (float)arg;
    ws_w[t] = w;
    ws_idx[t] = arg;
    atomicAdd(&counts[arg], 1);
  }
  __syncthreads();
  const int e = tid & 63, q = tid >> 6;
  float ps = 0.f;
  for (int r = 0; r < 32; ++r) ps += lp[q * 32 + r][e];
  psq[q][e] = ps;
  __syncthreads();
  if (tid < 64) {
    const float tot = ((psq[0][tid] + psq[1][tid]) + psq[2][tid]) + psq[3][tid];
    probsum[(size_t)blockIdx.x * EE + tid] = tot;
  }
}

// ---------------- K4: fused stats + select + apply (one 1024-thr block) ----
__device__ __forceinline__ int sr_bsum(int c, int red[][16], int pc, int tid) {
#pragma unroll
  for (int off = 32; off > 0; off >>= 1) c += __shfl_down(c, off, 64);
  if ((tid & 63) == 0) red[pc & 1][tid >> 6] = c;
  __syncthreads();
  int s = 0;
#pragma unroll
  for (int i = 0; i < 16; ++i) s += red[pc & 1][i];
  return s;
}

__global__ __launch_bounds__(1024) void sr_finish(
    const float* __restrict__ probsum, const int* __restrict__ counts,
    const float* __restrict__ ws_w, const int* __restrict__ ws_idx,
    float* __restrict__ dout, int N, int nblocks, int cap)
{
  __shared__ double dseg[16][EE];
  __shared__ double mean_s[EE];
  __shared__ int cnt_s[EE];
  __shared__ int hdr[2];
  __shared__ int red[2][16];
  const int tid = threadIdx.x;
  const int PER = N / 1024;  // 16

  float wv[16];
  int iv[16];
#pragma unroll
  for (int r = 0; r < 16; ++r) {
    float w = 0.f; int ix = -1;
    if (r < PER) {
      const int i = tid + r * 1024;
      w = ws_w[i];
      ix = ws_idx[i];
    }
    wv[r] = w; iv[r] = ix;
  }

  {
    const int e = tid & 63, seg = tid >> 6;
    const int per = nblocks / 16;
    double ps = 0.0;
    for (int b = seg * per; b < (seg + 1) * per; ++b)
      ps += (double)probsum[(size_t)b * EE + e];
    dseg[seg][e] = ps;
  }
  __syncthreads();
  if (tid < 64) {
    double tot = 0.0;
#pragma unroll
    for (int s2 = 0; s2 < 16; ++s2) tot += dseg[s2][tid];
    const int cnt = counts[tid];
    dout[2 * N + tid] = (float)cnt;
    mean_s[tid] = tot / (double)N;
    cnt_s[tid] = cnt;
  }
  __syncthreads();
  if (tid == 0) {
    double aux = 0.0;
    int nover = 0, e1 = -1;
    for (int i = 0; i < EE; ++i) {
      aux += ((double)cnt_s[i] / (double)N) * mean_s[i];
      if (cnt_s[i] > cap) { if (nover == 0) e1 = i; ++nover; }
    }
    dout[2 * N + EE] = (float)(aux * (double)EE);
    hdr[0] = (nover >= 2) ? 2 : nover;
    hdr[1] = e1;
  }
  __syncthreads();
  const int mode = hdr[0];

  if (mode == 0) return;
  if (mode == 2) {
#pragma unroll
    for (int r = 0; r < 16; ++r)
      if (r < PER) dout[tid + r * 1024] = 0.f;
    return;
  }

  const int e1 = hdr[1];
  unsigned mb[16];
#pragma unroll
  for (int r = 0; r < 16; ++r)
    mb[r] = (iv[r] == e1) ? __float_as_uint(wv[r]) : 0u;

  int pc = 0;
  unsigned lo = 0x3C000000u, hi = 0x3F800000u;
  while (hi - lo > 1u) {
    const unsigned mid = lo + ((hi - lo) >> 1);
    int c = 0;
#pragma unroll
    for (int r = 0; r < 16; ++r) c += (mb[r] >= mid);
    const int tot = sr_bsum(c, red, pc++, tid);
    if (tot >= cap) lo = mid; else hi = mid;
  }
  int cge = 0, cgt = 0;
#pragma unroll
  for (int r = 0; r < 16; ++r) {
    cge += (mb[r] >= lo);
    cgt += (mb[r] > lo);
  }
  const int tot_ge = sr_bsum(cge, red, pc++, tid);
  const int tot_gt = sr_bsum(cgt, red, pc++, tid);
  const int quota = cap - tot_gt;
  int idx_thr = N - 1;
  if (tot_ge - tot_gt > quota) {
    int l2 = -1, h2 = N - 1;
    while (h2 - l2 > 1) {
      const int mid = (l2 + h2) >> 1;
      int c = 0;
#pragma unroll
      for (int r = 0; r < 16; ++r) {
        const int i = tid + r * 1024;
        c += (mb[r] == lo && i <= mid) ? 1 : 0;
      }
      const int tot = sr_bsum(c, red, pc++, tid);
      if (tot >= quota) h2 = mid; else l2 = mid;
    }
    idx_thr = h2;
  }

#pragma unroll
  for (int r = 0; r < 16; ++r) {
    if (r < PER) {
      const int i = tid + r * 1024;
      const bool keep = (mb[r] > lo) || (mb[r] == lo && i <= idx_thr);
      dout[i] = keep ? wv[r] : 0.f;
    }
  }
}

// ---------------- launch ----------------
extern "C" void kernel_launch(void* const* d_in, const int* in_sizes, int n_in,
                              void* d_out, int out_size, void* d_ws, size_t ws_size,
                              hipStream_t stream)
{
  const float* x = (const float*)d_in[0];
  const float* wg = (const float*)d_in[1];
  const int N = in_sizes[0] / DD;  // 16384
  float* dout = (float*)d_out;
  float* wsf = (float*)d_ws;

  float* ws_w = wsf;
  int* ws_idx = (int*)(wsf + N);
  int* counts = (int*)(wsf + 2 * (size_t)N);
  float* probsum = wsf + 2 * (size_t)N + EE;
  const int nblocks_sm = N / 128;
  float* logits = wsf + 2 * (size_t)N + EE + (size_t)nblocks_sm * EE;
  float* partial = logits + (size_t)EE * N;
  const size_t base_floats = 2 * (size_t)N + EE + (size_t)nblocks_sm * EE + (size_t)EE * N;
  const int cap = (int)((double)N * 1.25 / (double)EE);  // 320

  const bool use16 =
      (base_floats + (size_t)16 * EE * (size_t)N) * sizeof(float) <= ws_size;

  if (use16) {
    sr_gemm16<<<(N / TOK16) * 16, 256, 0, stream>>>(x, wg, partial, N);
    sr_reduceT<16><<<(EE * N / 4 + 255) / 256, 256, 0, stream>>>(partial, logits, counts, N);
  } else {
    sr_gemm8<<<(N / TOKTILE) * 8, 256, 0, stream>>>(x, wg, partial, N);
    sr_reduceT<8><<<(EE * N / 4 + 255) / 256, 256, 0, stream>>>(partial, logits, counts, N);
  }
  sr_softmax<<<N / 128, 256, 0, stream>>>(logits, dout, ws_w, ws_idx, counts, probsum, N);
  sr_finish<<<1, 1024, 0, stream>>>(probsum, counts, ws_w, ws_idx, dout, N, nblocks_sm, cap);
}

// Round 21
// 140.233 us; speedup vs baseline: 1.0231x; 1.0194x over previous
//
#include <hip/hip_runtime.h>
#include <math.h>

#define DD 2048
#define EE 64
#define KQ 32
#define TOKTILE 128

// ---------------- K1a: gate GEMM, ksplit=8, 4x8 tile (R13 verbatim, 79us) ----
__global__ __launch_bounds__(256, 4) void sr_gemm8(
    const float* __restrict__ x, const float* __restrict__ wg,
    float* __restrict__ partial, int N)
{
  __shared__ float xs[KQ][TOKTILE];
  __shared__ float wsh[KQ][EE];
  const int ntiles = N / TOKTILE;
  const int tt = blockIdx.x % ntiles;
  const int kc = blockIdx.x / ntiles;
  const int kblk = DD / 8;
  const int nchunk = kblk / KQ;
  const int k0 = kc * kblk;
  const int t0 = tt * TOKTILE;
  const int tid = threadIdx.x;
  const int ti = tid & 31;
  const int tj = tid >> 5;

  float acc[4][8];
#pragma unroll
  for (int r = 0; r < 4; ++r)
#pragma unroll
    for (int c = 0; c < 8; ++c) acc[r][c] = 0.f;

  const int srowbase = tid >> 3;
  const int c4 = (tid & 7) * 4;
  const int swz = 8 * (tid & 3);

  for (int ch = 0; ch < nchunk; ++ch) {
    const int kb = k0 + ch * KQ;
#pragma unroll
    for (int p = 0; p < 4; ++p) {
      const int row = p * 32 + srowbase;
      const float4 v = *reinterpret_cast<const float4*>(
          &x[(size_t)(t0 + row) * DD + kb + c4]);
      const int srow = row ^ swz;
      xs[c4 + 0][srow] = v.x;
      xs[c4 + 1][srow] = v.y;
      xs[c4 + 2][srow] = v.z;
      xs[c4 + 3][srow] = v.w;
    }
    {
      const int e = tid >> 2;
      const int kq = (tid & 3) * 8;
      const float4 a = *reinterpret_cast<const float4*>(&wg[(size_t)e * DD + kb + kq]);
      const float4 b = *reinterpret_cast<const float4*>(&wg[(size_t)e * DD + kb + kq + 4]);
      wsh[kq + 0][e] = a.x; wsh[kq + 1][e] = a.y; wsh[kq + 2][e] = a.z; wsh[kq + 3][e] = a.w;
      wsh[kq + 4][e] = b.x; wsh[kq + 5][e] = b.y; wsh[kq + 6][e] = b.z; wsh[kq + 7][e] = b.w;
    }
    __syncthreads();
#pragma unroll 8
    for (int k = 0; k < KQ; ++k) {
      const int sk = 8 * ((k >> 2) & 3);
      float xv[4], wv[8];
      *reinterpret_cast<float4*>(&xv[0]) =
          *reinterpret_cast<const float4*>(&xs[k][(4 * ti) ^ sk]);
      *reinterpret_cast<float4*>(&wv[0]) = *reinterpret_cast<const float4*>(&wsh[k][8 * tj]);
      *reinterpret_cast<float4*>(&wv[4]) = *reinterpret_cast<const float4*>(&wsh[k][8 * tj + 4]);
#pragma unroll
      for (int r = 0; r < 4; ++r)
#pragma unroll
        for (int c = 0; c < 8; ++c) acc[r][c] = fmaf(xv[r], wv[c], acc[r][c]);
    }
    __syncthreads();
  }
#pragma unroll
  for (int c = 0; c < 8; ++c) {
    const int e = 8 * tj + c;
    const float4 v = make_float4(acc[0][c], acc[1][c], acc[2][c], acc[3][c]);
    *reinterpret_cast<float4*>(&partial[((size_t)kc * EE + e) * N + t0 + 4 * ti]) = v;
  }
}

// ---------------- K1b: gate GEMM, ksplit=16, 8x8 tile, named-float4 accs ----
// R19's correctness-passing geometry. Accs are 16 NAMED float4s (no local
// array -> nothing for SROA/regalloc to demote); __launch_bounds__(256,1) is
// the only allocator mode that ever exceeded 128 VGPR (R7: 188, no spill).
// Per-output fmaf chain ascending k — arithmetic identical to R19's pass.
#define TOK16 256
#define KQ2 16
#define SR_ROW(A, B, X)                                                   \
  A.x = fmaf(X, wv0.x, A.x); A.y = fmaf(X, wv0.y, A.y);                   \
  A.z = fmaf(X, wv0.z, A.z); A.w = fmaf(X, wv0.w, A.w);                   \
  B.x = fmaf(X, wv1.x, B.x); B.y = fmaf(X, wv1.y, B.y);                   \
  B.z = fmaf(X, wv1.z, B.z); B.w = fmaf(X, wv1.w, B.w);

__global__ __launch_bounds__(256, 1) void sr_gemm16(
    const float* __restrict__ x, const float* __restrict__ wg,
    float* __restrict__ partial, int N)
{
  __shared__ float xs[KQ2][TOK16];  // 16 KB, swizzled (t ^ 8*((k>>2)&3))
  __shared__ float wsh[KQ2][EE];    // 4 KB
  const int ntiles = N / TOK16;     // 64
  const int tt = blockIdx.x % ntiles;
  const int kc = blockIdx.x / ntiles;  // 0..15
  const int kblk = DD / 16;         // 128
  const int nchunk = kblk / KQ2;    // 8
  const int k0 = kc * kblk;
  const int t0 = tt * TOK16;
  const int tid = threadIdx.x;
  const int ti = tid & 31;   // token octet: tokens 8*ti .. 8*ti+7
  const int tj = tid >> 5;   // expert octet: experts 8*tj .. 8*tj+7

  // 16 named accumulators: row r (token 8ti+r) x {experts 8tj..+3, 8tj+4..+7}
  float4 z = make_float4(0.f, 0.f, 0.f, 0.f);
  float4 a0a = z, a0b = z, a1a = z, a1b = z, a2a = z, a2b = z, a3a = z, a3b = z;
  float4 a4a = z, a4b = z, a5a = z, a5b = z, a6a = z, a6b = z, a7a = z, a7b = z;

  // x staging: 4 passes x 64 rows; 4 thr/row (64B contiguous per row-chunk)
  const int srowb = tid >> 2;           // 0..63
  const int c4s = (tid & 3) * 4;        // k quad base (0..12)
  const int swz = 8 * (tid & 3);        // == 8*(((c4s+j)>>2)&3)
  // w staging: 4 thr/expert row, 4 k each
  const int we = tid >> 2;              // 0..63
  const int wk4 = (tid & 3) * 4;

  for (int ch = 0; ch < nchunk; ++ch) {
    const int kb = k0 + ch * KQ2;
#pragma unroll
    for (int p = 0; p < 4; ++p) {
      const int row = p * 64 + srowb;
      const float4 v = *reinterpret_cast<const float4*>(
          &x[(size_t)(t0 + row) * DD + kb + c4s]);
      const int srow = row ^ swz;       // 2-way bank spread on writes
      xs[c4s + 0][srow] = v.x;
      xs[c4s + 1][srow] = v.y;
      xs[c4s + 2][srow] = v.z;
      xs[c4s + 3][srow] = v.w;
    }
    {
      const float4 a = *reinterpret_cast<const float4*>(
          &wg[(size_t)we * DD + kb + wk4]);
      wsh[wk4 + 0][we] = a.x;
      wsh[wk4 + 1][we] = a.y;
      wsh[wk4 + 2][we] = a.z;
      wsh[wk4 + 3][we] = a.w;
    }
    __syncthreads();
#pragma unroll
    for (int k = 0; k < KQ2; ++k) {
      const int sk = 8 * ((k >> 2) & 3);
      const int xb = (8 * ti) ^ sk;  // +4 stays in-range: sk has no bits 0-2
      const float4 xva = *reinterpret_cast<const float4*>(&xs[k][xb]);
      const float4 xvb = *reinterpret_cast<const float4*>(&xs[k][xb + 4]);
      const float4 wv0 = *reinterpret_cast<const float4*>(&wsh[k][8 * tj]);
      const float4 wv1 = *reinterpret_cast<const float4*>(&wsh[k][8 * tj + 4]);
      SR_ROW(a0a, a0b, xva.x)
      SR_ROW(a1a, a1b, xva.y)
      SR_ROW(a2a, a2b, xva.z)
      SR_ROW(a3a, a3b, xva.w)
      SR_ROW(a4a, a4b, xvb.x)
      SR_ROW(a5a, a5b, xvb.y)
      SR_ROW(a6a, a6b, xvb.z)
      SR_ROW(a7a, a7b, xvb.w)
    }
    __syncthreads();
  }
  // partial[kc][e][t]: transpose in registers -> token-contiguous float4s
  {
    const size_t b0 = ((size_t)kc * EE + 8 * tj) * N + t0 + 8 * ti;
    float4* p;
    p = reinterpret_cast<float4*>(&partial[b0 + 0 * N]);
    p[0] = make_float4(a0a.x, a1a.x, a2a.x, a3a.x);
    p[1] = make_float4(a4a.x, a5a.x, a6a.x, a7a.x);
    p = reinterpret_cast<float4*>(&partial[b0 + 1 * N]);
    p[0] = make_float4(a0a.y, a1a.y, a2a.y, a3a.y);
    p[1] = make_float4(a4a.y, a5a.y, a6a.y, a7a.y);
    p = reinterpret_cast<float4*>(&partial[b0 + 2 * N]);
    p[0] = make_float4(a0a.z, a1a.z, a2a.z, a3a.z);
    p[1] = make_float4(a4a.z, a5a.z, a6a.z, a7a.z);
    p = reinterpret_cast<float4*>(&partial[b0 + 3 * N]);
    p[0] = make_float4(a0a.w, a1a.w, a2a.w, a3a.w);
    p[1] = make_float4(a4a.w, a5a.w, a6a.w, a7a.w);
    p = reinterpret_cast<float4*>(&partial[b0 + 4 * N]);
    p[0] = make_float4(a0b.x, a1b.x, a2b.x, a3b.x);
    p[1] = make_float4(a4b.x, a5b.x, a6b.x, a7b.x);
    p = reinterpret_cast<float4*>(&partial[b0 + 5 * N]);
    p[0] = make_float4(a0b.y, a1b.y, a2b.y, a3b.y);
    p[1] = make_float4(a4b.y, a5b.y, a6b.y, a7b.y);
    p = reinterpret_cast<float4*>(&partial[b0 + 6 * N]);
    p[0] = make_float4(a0b.z, a1b.z, a2b.z, a3b.z);
    p[1] = make_float4(a4b.z, a5b.z, a6b.z, a7b.z);
    p = reinterpret_cast<float4*>(&partial[b0 + 7 * N]);
    p[0] = make_float4(a0b.w, a1b.w, a2b.w, a3b.w);
    p[1] = make_float4(a4b.w, a5b.w, a6b.w, a7b.w);
  }
}

// ---------------- K2: cross-ksplit reduction (templated, unrolled) ----------
template <int KS>
__global__ __launch_bounds__(256) void sr_reduceT(
    const float* __restrict__ partial, float* __restrict__ logits,
    int* __restrict__ counts, int N)
{
  if (blockIdx.x == 0 && threadIdx.x < EE) counts[threadIdx.x] = 0;
  const int i4 = blockIdx.x * 256 + threadIdx.x;
  const size_t base = (size_t)i4 * 4;
  if (base >= (size_t)EE * N) return;
  const size_t cs = (size_t)EE * N;
  double s0 = 0.0, s1 = 0.0, s2 = 0.0, s3 = 0.0;
#pragma unroll
  for (int c = 0; c < KS; ++c) {
    const float4 v = *reinterpret_cast<const float4*>(&partial[c * cs + base]);
    s0 += (double)v.x; s1 += (double)v.y; s2 += (double)v.z; s3 += (double)v.w;
  }
  *reinterpret_cast<float4*>(&logits[base]) =
      make_float4((float)s0, (float)s1, (float)s2, (float)s3);
}

// ---------------- K3: per-token softmax/argmax (128 tok / 256 thr blocks) ----
__global__ __launch_bounds__(256) void sr_softmax(
    const float* __restrict__ logits, float* __restrict__ dout,
    float* __restrict__ ws_w, int* __restrict__ ws_idx,
    int* __restrict__ counts, float* __restrict__ probsum, int N)
{
  __shared__ float lp[128][EE + 1];
  __shared__ float psq[4][EE];
  const int tid = threadIdx.x;
  const int t0 = blockIdx.x * 128;
  if (tid < 128) {
    const int t = t0 + tid;
    float l[EE];
    float maxv = -3.0e38f;
    int arg = 0;
#pragma unroll
    for (int e = 0; e < EE; ++e) {
      l[e] = logits[(size_t)e * N + t];
      if (l[e] > maxv) { maxv = l[e]; arg = e; }  // strict > : first max wins
    }
    float s = 0.f;
#pragma unroll
    for (int e = 0; e < EE; ++e) {
      const float ex = __expf(l[e] - maxv);
      lp[tid][e] = ex;
      s += ex;
    }
    const float inv = 1.0f / s;
    const float w = inv;  // exp(0)/sum
#pragma unroll
    for (int e = 0; e < EE; ++e) lp[tid][e] *= inv;
    dout[t] = w;
    dout[N + t] = (float)arg;
    ws_w[t] = w;
    ws_idx[t] = arg;
    atomicAdd(&counts[arg], 1);
  }
  __syncthreads();
  const int e = tid & 63, q = tid >> 6;
  float ps = 0.f;
  for (int r = 0; r < 32; ++r) ps += lp[q * 32 + r][e];
  psq[q][e] = ps;
  __syncthreads();
  if (tid < 64) {
    const float tot = ((psq[0][tid] + psq[1][tid]) + psq[2][tid]) + psq[3][tid];
    probsum[(size_t)blockIdx.x * EE + tid] = tot;
  }
}

// ---------------- K4: fused stats + select + apply (one 1024-thr block) ----
__device__ __forceinline__ int sr_bsum(int c, int red[][16], int pc, int tid) {
#pragma unroll
  for (int off = 32; off > 0; off >>= 1) c += __shfl_down(c, off, 64);
  if ((tid & 63) == 0) red[pc & 1][tid >> 6] = c;
  __syncthreads();
  int s = 0;
#pragma unroll
  for (int i = 0; i < 16; ++i) s += red[pc & 1][i];
  return s;
}

__global__ __launch_bounds__(1024) void sr_finish(
    const float* __restrict__ probsum, const int* __restrict__ counts,
    const float* __restrict__ ws_w, const int* __restrict__ ws_idx,
    float* __restrict__ dout, int N, int nblocks, int cap)
{
  __shared__ double dseg[16][EE];
  __shared__ double mean_s[EE];
  __shared__ int cnt_s[EE];
  __shared__ int hdr[2];
  __shared__ int red[2][16];
  const int tid = threadIdx.x;
  const int PER = N / 1024;  // 16

  float wv[16];
  int iv[16];
#pragma unroll
  for (int r = 0; r < 16; ++r) {
    float w = 0.f; int ix = -1;
    if (r < PER) {
      const int i = tid + r * 1024;
      w = ws_w[i];
      ix = ws_idx[i];
    }
    wv[r] = w; iv[r] = ix;
  }

  {
    const int e = tid & 63, seg = tid >> 6;
    const int per = nblocks / 16;
    double ps = 0.0;
    for (int b = seg * per; b < (seg + 1) * per; ++b)
      ps += (double)probsum[(size_t)b * EE + e];
    dseg[seg][e] = ps;
  }
  __syncthreads();
  if (tid < 64) {
    double tot = 0.0;
#pragma unroll
    for (int s2 = 0; s2 < 16; ++s2) tot += dseg[s2][tid];
    const int cnt = counts[tid];
    dout[2 * N + tid] = (float)cnt;
    mean_s[tid] = tot / (double)N;
    cnt_s[tid] = cnt;
  }
  __syncthreads();
  if (tid == 0) {
    double aux = 0.0;
    int nover = 0, e1 = -1;
    for (int i = 0; i < EE; ++i) {
      aux += ((double)cnt_s[i] / (double)N) * mean_s[i];
      if (cnt_s[i] > cap) { if (nover == 0) e1 = i; ++nover; }
    }
    dout[2 * N + EE] = (float)(aux * (double)EE);
    hdr[0] = (nover >= 2) ? 2 : nover;
    hdr[1] = e1;
  }
  __syncthreads();
  const int mode = hdr[0];

  if (mode == 0) return;
  if (mode == 2) {
#pragma unroll
    for (int r = 0; r < 16; ++r)
      if (r < PER) dout[tid + r * 1024] = 0.f;
    return;
  }

  const int e1 = hdr[1];
  unsigned mb[16];
#pragma unroll
  for (int r = 0; r < 16; ++r)
    mb[r] = (iv[r] == e1) ? __float_as_uint(wv[r]) : 0u;

  int pc = 0;
  unsigned lo = 0x3C000000u, hi = 0x3F800000u;
  while (hi - lo > 1u) {
    const unsigned mid = lo + ((hi - lo) >> 1);
    int c = 0;
#pragma unroll
    for (int r = 0; r < 16; ++r) c += (mb[r] >= mid);
    const int tot = sr_bsum(c, red, pc++, tid);
    if (tot >= cap) lo = mid; else hi = mid;
  }
  int cge = 0, cgt = 0;
#pragma unroll
  for (int r = 0; r < 16; ++r) {
    cge += (mb[r] >= lo);
    cgt += (mb[r] > lo);
  }
  const int tot_ge = sr_bsum(cge, red, pc++, tid);
  const int tot_gt = sr_bsum(cgt, red, pc++, tid);
  const int quota = cap - tot_gt;
  int idx_thr = N - 1;
  if (tot_ge - tot_gt > quota) {
    int l2 = -1, h2 = N - 1;
    while (h2 - l2 > 1) {
      const int mid = (l2 + h2) >> 1;
      int c = 0;
#pragma unroll
      for (int r = 0; r < 16; ++r) {
        const int i = tid + r * 1024;
        c += (mb[r] == lo && i <= mid) ? 1 : 0;
      }
      const int tot = sr_bsum(c, red, pc++, tid);
      if (tot >= quota) h2 = mid; else l2 = mid;
    }
    idx_thr = h2;
  }

#pragma unroll
  for (int r = 0; r < 16; ++r) {
    if (r < PER) {
      const int i = tid + r * 1024;
      const bool keep = (mb[r] > lo) || (mb[r] == lo && i <= idx_thr);
      dout[i] = keep ? wv[r] : 0.f;
    }
  }
}

// ---------------- launch ----------------
extern "C" void kernel_launch(void* const* d_in, const int* in_sizes, int n_in,
                              void* d_out, int out_size, void* d_ws, size_t ws_size,
                              hipStream_t stream)
{
  const float* x = (const float*)d_in[0];
  const float* wg = (const float*)d_in[1];
  const int N = in_sizes[0] / DD;  // 16384
  float* dout = (float*)d_out;
  float* wsf = (float*)d_ws;

  float* ws_w = wsf;
  int* ws_idx = (int*)(wsf + N);
  int* counts = (int*)(wsf + 2 * (size_t)N);
  float* probsum = wsf + 2 * (size_t)N + EE;
  const int nblocks_sm = N / 128;
  float* logits = wsf + 2 * (size_t)N + EE + (size_t)nblocks_sm * EE;
  float* partial = logits + (size_t)EE * N;
  const size_t base_floats = 2 * (size_t)N + EE + (size_t)nblocks_sm * EE + (size_t)EE * N;
  const int cap = (int)((double)N * 1.25 / (double)EE);  // 320

  const bool use16 =
      (base_floats + (size_t)16 * EE * (size_t)N) * sizeof(float) <= ws_size;

  if (use16) {
    sr_gemm16<<<(N / TOK16) * 16, 256, 0, stream>>>(x, wg, partial, N);
    sr_reduceT<16><<<(EE * N / 4 + 255) / 256, 256, 0, stream>>>(partial, logits, counts, N);
  } else {
    sr_gemm8<<<(N / TOKTILE) * 8, 256, 0, stream>>>(x, wg, partial, N);
    sr_reduceT<8><<<(EE * N / 4 + 255) / 256, 256, 0, stream>>>(partial, logits, counts, N);
  }
  sr_softmax<<<N / 128, 256, 0, stream>>>(logits, dout, ws_w, ws_idx, counts, probsum, N);
  sr_finish<<<1, 1024, 0, stream>>>(probsum, counts, ws_w, ws_idx, dout, N, nblocks_sm, cap);
}

// Round 22
// 133.174 us; speedup vs baseline: 1.0773x; 1.0530x over previous
//
#include <hip/hip_runtime.h>
#include <math.h>

#define DD 2048
#define EE 64
#define KQ 32
#define TOKTILE 128
#define KSPLIT 8

// ---------------- K1: gate GEMM, ksplit=8, 4x8 tile (proven 79us) ----------
// Two-barrier structure at 4 blocks/CU (4 waves/SIMD). DS-pipe-capped at
// VALU ~44% (3 ds_read_b128 per wave-k vs 64 FMA-issue cycles) — measured
// 43.7-45.4% across R5/R9/R13/R18. Every restructuring regressed: SGPR-w
// (R6), reg-prefetch (R8), global-w (R10), 8x8 tiles (R11/R17/R19/R20/R21 —
// hipcc regalloc caps VGPR at ~68 and spills). Do not touch.
__global__ __launch_bounds__(256, 4) void sr_gemm8(
    const float* __restrict__ x, const float* __restrict__ wg,
    float* __restrict__ partial, int N)
{
  __shared__ float xs[KQ][TOKTILE];  // 16 KB, swizzled (t ^ 8*((k>>2)&3))
  __shared__ float wsh[KQ][EE];      // 8 KB
  const int ntiles = N / TOKTILE;
  const int tt = blockIdx.x % ntiles;
  const int kc = blockIdx.x / ntiles;
  const int kblk = DD / KSPLIT;
  const int nchunk = kblk / KQ;
  const int k0 = kc * kblk;
  const int t0 = tt * TOKTILE;
  const int tid = threadIdx.x;
  const int ti = tid & 31;
  const int tj = tid >> 5;

  float acc[4][8];
#pragma unroll
  for (int r = 0; r < 4; ++r)
#pragma unroll
    for (int c = 0; c < 8; ++c) acc[r][c] = 0.f;

  const int srowbase = tid >> 3;
  const int c4 = (tid & 7) * 4;
  const int swz = 8 * (tid & 3);

  for (int ch = 0; ch < nchunk; ++ch) {
    const int kb = k0 + ch * KQ;
#pragma unroll
    for (int p = 0; p < 4; ++p) {
      const int row = p * 32 + srowbase;
      const float4 v = *reinterpret_cast<const float4*>(
          &x[(size_t)(t0 + row) * DD + kb + c4]);
      const int srow = row ^ swz;
      xs[c4 + 0][srow] = v.x;
      xs[c4 + 1][srow] = v.y;
      xs[c4 + 2][srow] = v.z;
      xs[c4 + 3][srow] = v.w;
    }
    {
      const int e = tid >> 2;
      const int kq = (tid & 3) * 8;
      const float4 a = *reinterpret_cast<const float4*>(&wg[(size_t)e * DD + kb + kq]);
      const float4 b = *reinterpret_cast<const float4*>(&wg[(size_t)e * DD + kb + kq + 4]);
      wsh[kq + 0][e] = a.x; wsh[kq + 1][e] = a.y; wsh[kq + 2][e] = a.z; wsh[kq + 3][e] = a.w;
      wsh[kq + 4][e] = b.x; wsh[kq + 5][e] = b.y; wsh[kq + 6][e] = b.z; wsh[kq + 7][e] = b.w;
    }
    __syncthreads();
#pragma unroll 8
    for (int k = 0; k < KQ; ++k) {
      const int sk = 8 * ((k >> 2) & 3);
      float xv[4], wv[8];
      *reinterpret_cast<float4*>(&xv[0]) =
          *reinterpret_cast<const float4*>(&xs[k][(4 * ti) ^ sk]);
      *reinterpret_cast<float4*>(&wv[0]) = *reinterpret_cast<const float4*>(&wsh[k][8 * tj]);
      *reinterpret_cast<float4*>(&wv[4]) = *reinterpret_cast<const float4*>(&wsh[k][8 * tj + 4]);
#pragma unroll
      for (int r = 0; r < 4; ++r)
#pragma unroll
        for (int c = 0; c < 8; ++c) acc[r][c] = fmaf(xv[r], wv[c], acc[r][c]);
    }
    __syncthreads();
  }
#pragma unroll
  for (int c = 0; c < 8; ++c) {
    const int e = 8 * tj + c;
    const float4 v = make_float4(acc[0][c], acc[1][c], acc[2][c], acc[3][c]);
    *reinterpret_cast<float4*>(&partial[((size_t)kc * EE + e) * N + t0 + 4 * ti]) = v;
  }
}

// ---------------- K2: cross-ksplit reduction -> logits[e][t] (+zero counts) --
// f64 sum in fixed c-order, compile-time unrolled (pipelined loads):
// bitwise-identical to the passing path.
__global__ __launch_bounds__(256) void sr_reduce(
    const float* __restrict__ partial, float* __restrict__ logits,
    int* __restrict__ counts, int N)
{
  if (blockIdx.x == 0 && threadIdx.x < EE) counts[threadIdx.x] = 0;
  const int i4 = blockIdx.x * 256 + threadIdx.x;
  const size_t base = (size_t)i4 * 4;
  if (base >= (size_t)EE * N) return;
  const size_t cs = (size_t)EE * N;
  double s0 = 0.0, s1 = 0.0, s2 = 0.0, s3 = 0.0;
#pragma unroll
  for (int c = 0; c < KSPLIT; ++c) {
    const float4 v = *reinterpret_cast<const float4*>(&partial[c * cs + base]);
    s0 += (double)v.x; s1 += (double)v.y; s2 += (double)v.z; s3 += (double)v.w;
  }
  *reinterpret_cast<float4*>(&logits[base]) =
      make_float4((float)s0, (float)s1, (float)s2, (float)s3);
}

// ---------------- K3: per-token softmax/argmax (128 tok / 256 thr blocks) ----
__global__ __launch_bounds__(256) void sr_softmax(
    const float* __restrict__ logits, float* __restrict__ dout,
    float* __restrict__ ws_w, int* __restrict__ ws_idx,
    int* __restrict__ counts, float* __restrict__ probsum, int N)
{
  __shared__ float lp[128][EE + 1];
  __shared__ float psq[4][EE];
  const int tid = threadIdx.x;
  const int t0 = blockIdx.x * 128;
  if (tid < 128) {
    const int t = t0 + tid;
    float l[EE];
    float maxv = -3.0e38f;
    int arg = 0;
#pragma unroll
    for (int e = 0; e < EE; ++e) {
      l[e] = logits[(size_t)e * N + t];
      if (l[e] > maxv) { maxv = l[e]; arg = e; }  // strict > : first max wins
    }
    float s = 0.f;
#pragma unroll
    for (int e = 0; e < EE; ++e) {
      const float ex = __expf(l[e] - maxv);
      lp[tid][e] = ex;
      s += ex;
    }
    const float inv = 1.0f / s;
    const float w = inv;  // exp(0)/sum
#pragma unroll
    for (int e = 0; e < EE; ++e) lp[tid][e] *= inv;
    dout[t] = w;
    dout[N + t] = (float)arg;
    ws_w[t] = w;
    ws_idx[t] = arg;
    atomicAdd(&counts[arg], 1);
  }
  __syncthreads();
  const int e = tid & 63, q = tid >> 6;
  float ps = 0.f;
  for (int r = 0; r < 32; ++r) ps += lp[q * 32 + r][e];
  psq[q][e] = ps;
  __syncthreads();
  if (tid < 64) {
    const float tot = ((psq[0][tid] + psq[1][tid]) + psq[2][tid]) + psq[3][tid];
    probsum[(size_t)blockIdx.x * EE + tid] = tot;
  }
}

// ---------------- K4: fused stats + select + apply (one 1024-thr block) ----
__device__ __forceinline__ int sr_bsum(int c, int red[][16], int pc, int tid) {
#pragma unroll
  for (int off = 32; off > 0; off >>= 1) c += __shfl_down(c, off, 64);
  if ((tid & 63) == 0) red[pc & 1][tid >> 6] = c;
  __syncthreads();
  int s = 0;
#pragma unroll
  for (int i = 0; i < 16; ++i) s += red[pc & 1][i];
  return s;
}

__global__ __launch_bounds__(1024) void sr_finish(
    const float* __restrict__ probsum, const int* __restrict__ counts,
    const float* __restrict__ ws_w, const int* __restrict__ ws_idx,
    float* __restrict__ dout, int N, int nblocks, int cap)
{
  __shared__ double dseg[16][EE];
  __shared__ double mean_s[EE];
  __shared__ int cnt_s[EE];
  __shared__ int hdr[2];
  __shared__ int red[2][16];
  const int tid = threadIdx.x;
  const int PER = N / 1024;  // 16

  float wv[16];
  int iv[16];
#pragma unroll
  for (int r = 0; r < 16; ++r) {
    float w = 0.f; int ix = -1;
    if (r < PER) {
      const int i = tid + r * 1024;
      w = ws_w[i];
      ix = ws_idx[i];
    }
    wv[r] = w; iv[r] = ix;
  }

  {
    const int e = tid & 63, seg = tid >> 6;
    const int per = nblocks / 16;
    double ps = 0.0;
    for (int b = seg * per; b < (seg + 1) * per; ++b)
      ps += (double)probsum[(size_t)b * EE + e];
    dseg[seg][e] = ps;
  }
  __syncthreads();
  if (tid < 64) {
    double tot = 0.0;
#pragma unroll
    for (int s2 = 0; s2 < 16; ++s2) tot += dseg[s2][tid];
    const int cnt = counts[tid];
    dout[2 * N + tid] = (float)cnt;
    mean_s[tid] = tot / (double)N;
    cnt_s[tid] = cnt;
  }
  __syncthreads();
  if (tid == 0) {
    double aux = 0.0;
    int nover = 0, e1 = -1;
    for (int i = 0; i < EE; ++i) {
      aux += ((double)cnt_s[i] / (double)N) * mean_s[i];
      if (cnt_s[i] > cap) { if (nover == 0) e1 = i; ++nover; }
    }
    dout[2 * N + EE] = (float)(aux * (double)EE);
    hdr[0] = (nover >= 2) ? 2 : nover;
    hdr[1] = e1;
  }
  __syncthreads();
  const int mode = hdr[0];

  if (mode == 0) return;  // softmax already wrote dout[t] = w
  if (mode == 2) {        // carried zeroing kills all weights
#pragma unroll
    for (int r = 0; r < 16; ++r)
      if (r < PER) dout[tid + r * 1024] = 0.f;
    return;
  }

  const int e1 = hdr[1];
  unsigned mb[16];
#pragma unroll
  for (int r = 0; r < 16; ++r)
    mb[r] = (iv[r] == e1) ? __float_as_uint(wv[r]) : 0u;

  int pc = 0;
  // w = 1/softmax_sum in [1/64, 1): search bits in [0x3C000000, 0x3F800000)
  unsigned lo = 0x3C000000u, hi = 0x3F800000u;
  while (hi - lo > 1u) {
    const unsigned mid = lo + ((hi - lo) >> 1);
    int c = 0;
#pragma unroll
    for (int r = 0; r < 16; ++r) c += (mb[r] >= mid);
    const int tot = sr_bsum(c, red, pc++, tid);
    if (tot >= cap) lo = mid; else hi = mid;
  }
  int cge = 0, cgt = 0;
#pragma unroll
  for (int r = 0; r < 16; ++r) {
    cge += (mb[r] >= lo);
    cgt += (mb[r] > lo);
  }
  const int tot_ge = sr_bsum(cge, red, pc++, tid);
  const int tot_gt = sr_bsum(cgt, red, pc++, tid);
  const int quota = cap - tot_gt;
  int idx_thr = N - 1;
  if (tot_ge - tot_gt > quota) {
    // tie at tau: keep the quota lowest-index equals (lax.top_k tie-break)
    int l2 = -1, h2 = N - 1;
    while (h2 - l2 > 1) {
      const int mid = (l2 + h2) >> 1;
      int c = 0;
#pragma unroll
      for (int r = 0; r < 16; ++r) {
        const int i = tid + r * 1024;
        c += (mb[r] == lo && i <= mid) ? 1 : 0;
      }
      const int tot = sr_bsum(c, red, pc++, tid);
      if (tot >= quota) h2 = mid; else l2 = mid;
    }
    idx_thr = h2;
  }

#pragma unroll
  for (int r = 0; r < 16; ++r) {
    if (r < PER) {
      const int i = tid + r * 1024;
      const bool keep = (mb[r] > lo) || (mb[r] == lo && i <= idx_thr);
      dout[i] = keep ? wv[r] : 0.f;
    }
  }
}

// ---------------- launch ----------------
extern "C" void kernel_launch(void* const* d_in, const int* in_sizes, int n_in,
                              void* d_out, int out_size, void* d_ws, size_t ws_size,
                              hipStream_t stream)
{
  const float* x = (const float*)d_in[0];
  const float* wg = (const float*)d_in[1];
  const int N = in_sizes[0] / DD;  // 16384
  float* dout = (float*)d_out;
  float* wsf = (float*)d_ws;

  // ws layout (floats):
  // [ws_w N][ws_idx N][counts 64][probsum (N/128)*64][logits EE*N][partial ...]
  float* ws_w = wsf;
  int* ws_idx = (int*)(wsf + N);
  int* counts = (int*)(wsf + 2 * (size_t)N);
  float* probsum = wsf + 2 * (size_t)N + EE;
  const int nblocks_sm = N / 128;
  float* logits = wsf + 2 * (size_t)N + EE + (size_t)nblocks_sm * EE;
  float* partial = logits + (size_t)EE * N;
  const int cap = (int)((double)N * 1.25 / (double)EE);  // 320

  sr_gemm8<<<(N / TOKTILE) * KSPLIT, 256, 0, stream>>>(x, wg, partial, N);
  sr_reduce<<<(EE * N / 4 + 255) / 256, 256, 0, stream>>>(partial, logits, counts, N);
  sr_softmax<<<N / 128, 256, 0, stream>>>(logits, dout, ws_w, ws_idx, counts, probsum, N);
  sr_finish<<<1, 1024, 0, stream>>>(probsum, counts, ws_w, ws_idx, dout, N, nblocks_sm, cap);
}